// Round 4
// baseline (139.954 us; speedup 1.0000x reference)
//
#include <hip/hip_runtime.h>
#include <hip/hip_bf16.h>

// Problem constants (from reference)
constexpr int kB   = 16384;   // batch
constexpr int kNeg = 10;      // negatives per example
constexpr int kE   = 128;     // embedding dim
constexpr int kWavesPerBlock = 4;                 // 256 threads
constexpr int kExPerWave     = 2;                 // 32 lanes per example
constexpr int kBlocks = kB / (kWavesPerBlock * kExPerWave);   // 2048

__device__ __forceinline__ float log_sigmoid(float x) {
    // numerically stable: min(x,0) - log1p(exp(-|x|))
    return fminf(x, 0.0f) - log1pf(expf(-fabsf(x)));
}

__device__ __forceinline__ float dot4(float4 a, float4 b) {
    return a.x * b.x + a.y * b.y + a.z * b.z + a.w * b.w;
}

// 32 lanes per example, 2 examples per wave. All 24 per-wave indices are
// loaded through wave-uniform (SGPR / s_load) addresses: b0 is forced
// uniform via readfirstlane so the compiler emits scalar loads instead of
// 12 broadcast vector loads per lane.
__global__ __launch_bounds__(256, 4) void w2v_loss_kernel(
    const int*   __restrict__ input_word,
    const int*   __restrict__ context_word,
    const int*   __restrict__ noise_words,
    const float* __restrict__ W_in,
    const float* __restrict__ W_ctx,
    float*       __restrict__ out)
{
    const int lane = threadIdx.x & 63;
    const int wave = threadIdx.x >> 6;
    const int half = lane >> 5;               // which example of the wave
    const int l32  = lane & 31;               // lane within 32-lane group

    // wave-uniform example base (b0, b0+1 are this wave's two examples)
    const int wg_u = __builtin_amdgcn_readfirstlane(
        blockIdx.x * kWavesPerBlock + (threadIdx.x >> 6));
    const int b0 = wg_u * kExPerWave;

    // Wave-uniform index loads -> scalar cache (s_load).
    const int iw0 = input_word[b0],   iw1 = input_word[b0 + 1];
    const int cw0 = context_word[b0], cw1 = context_word[b0 + 1];
    int nwall[2 * kNeg];
    #pragma unroll
    for (int j = 0; j < 2 * kNeg; ++j)
        nwall[j] = noise_words[b0 * kNeg + j];   // contiguous 20-int block

    // Per-half selection (v_cndmask, no memory traffic).
    const int iw = half ? iw1 : iw0;
    const int cw = half ? cw1 : cw0;

    // Issue all 12 row gathers back-to-back (1 float4/lane, coalesced 512B/row).
    const float4 c = ((const float4*)(W_in  + (size_t)iw * kE))[l32];
    const float4 x = ((const float4*)(W_ctx + (size_t)cw * kE))[l32];
    float4 nv[kNeg];
    #pragma unroll
    for (int k = 0; k < kNeg; ++k) {
        const int nw = half ? nwall[kNeg + k] : nwall[k];
        nv[k] = ((const float4*)(W_ctx + (size_t)nw * kE))[l32];
    }

    float pos = dot4(c, x);
    float negp[kNeg];
    #pragma unroll
    for (int k = 0; k < kNeg; ++k)
        negp[k] = dot4(c, nv[k]);

    // 5-step butterfly within each 32-lane half (xor masks < 32 stay in-half).
    #pragma unroll
    for (int off = 16; off > 0; off >>= 1) {
        pos += __shfl_xor(pos, off);
        #pragma unroll
        for (int k = 0; k < kNeg; ++k)
            negp[k] += __shfl_xor(negp[k], off);
    }
    // Every lane now holds all 11 full dot products for its example.

    // Distribute the 11 log_sigmoid evaluations across lanes 0..10 of the half.
    float v = pos;                          // lane 0: positive score
    #pragma unroll
    for (int k = 0; k < kNeg; ++k)
        v = (l32 == k + 1) ? -negp[k] : v;  // lanes 1..10: negated neg scores
    float s = (l32 < 1 + kNeg) ? log_sigmoid(v) : 0.0f;

    // Sum the 11 terms within the half (5 steps), then across halves (1 step).
    #pragma unroll
    for (int off = 16; off > 0; off >>= 1)
        s += __shfl_xor(s, off);
    s += __shfl_xor(s, 32);

    __shared__ float smem[kWavesPerBlock];
    if (lane == 0) smem[wave] = s;
    __syncthreads();
    if (threadIdx.x == 0) {
        const float t = smem[0] + smem[1] + smem[2] + smem[3];
        atomicAdd(out, t * (-1.0f / (float)kB));   // device-scope fp32 atomic
    }
}

extern "C" void kernel_launch(void* const* d_in, const int* in_sizes, int n_in,
                              void* d_out, int out_size, void* d_ws, size_t ws_size,
                              hipStream_t stream) {
    const int*   input_word   = (const int*)d_in[0];
    const int*   context_word = (const int*)d_in[1];
    const int*   noise_words  = (const int*)d_in[2];
    const float* W_in         = (const float*)d_in[3];
    const float* W_ctx        = (const float*)d_in[4];
    float*       out          = (float*)d_out;

    // d_out is poisoned before every timed replay; zero it on-stream
    // (memset nodes are graph-capturable), then accumulate atomically.
    hipMemsetAsync(out, 0, sizeof(float), stream);
    w2v_loss_kernel<<<kBlocks, 256, 0, stream>>>(
        input_word, context_word, noise_words, W_in, W_ctx, out);
}

// Round 5
// 125.247 us; speedup vs baseline: 1.1174x; 1.1174x over previous
//
#include <hip/hip_runtime.h>
#include <hip/hip_bf16.h>

// Problem constants (from reference)
constexpr int kB   = 16384;   // batch
constexpr int kNeg = 10;      // negatives per example
constexpr int kE   = 128;     // embedding dim
constexpr int kWavesPerBlock = 4;                 // 256 threads
constexpr int kExPerWave     = 2;                 // 32 lanes per example
constexpr int kBlocks = kB / (kWavesPerBlock * kExPerWave);   // 2048

__device__ __forceinline__ float log_sigmoid(float x) {
    // numerically stable: min(x,0) - log1p(exp(-|x|))
    return fminf(x, 0.0f) - log1pf(expf(-fabsf(x)));
}

__device__ __forceinline__ float dot4(float4 a, float4 b) {
    return a.x * b.x + a.y * b.y + a.z * b.z + a.w * b.w;
}

// 32 lanes per example, 2 examples per wave. The 24 per-wave indices are
// loaded through wave-uniform addresses (readfirstlane -> s_load scalar
// cache), freeing the vector pipe; the 12 row gathers per lane issue
// back-to-back (1 float4/lane, coalesced 512B/row). Per-block partials ->
// d_ws; tiny second kernel reduces (NO same-address atomics: R4 showed
// 2048 same-address atomicAdds cost ~15us of serialization).
__global__ __launch_bounds__(256, 4) void w2v_loss_kernel(
    const int*   __restrict__ input_word,
    const int*   __restrict__ context_word,
    const int*   __restrict__ noise_words,
    const float* __restrict__ W_in,
    const float* __restrict__ W_ctx,
    float*       __restrict__ partials)
{
    const int lane = threadIdx.x & 63;
    const int wave = threadIdx.x >> 6;
    const int half = lane >> 5;               // which example of the wave
    const int l32  = lane & 31;               // lane within 32-lane group

    // wave-uniform example base (b0, b0+1 are this wave's two examples)
    const int wg_u = __builtin_amdgcn_readfirstlane(
        blockIdx.x * kWavesPerBlock + (threadIdx.x >> 6));
    const int b0 = wg_u * kExPerWave;

    // Wave-uniform index loads -> scalar cache (s_load).
    const int iw0 = input_word[b0],   iw1 = input_word[b0 + 1];
    const int cw0 = context_word[b0], cw1 = context_word[b0 + 1];
    int nwall[2 * kNeg];
    #pragma unroll
    for (int j = 0; j < 2 * kNeg; ++j)
        nwall[j] = noise_words[b0 * kNeg + j];   // contiguous 20-int block

    // Per-half selection (v_cndmask, no memory traffic).
    const int iw = half ? iw1 : iw0;
    const int cw = half ? cw1 : cw0;

    // Issue all 12 row gathers back-to-back.
    const float4 c = ((const float4*)(W_in  + (size_t)iw * kE))[l32];
    const float4 x = ((const float4*)(W_ctx + (size_t)cw * kE))[l32];
    float4 nv[kNeg];
    #pragma unroll
    for (int k = 0; k < kNeg; ++k) {
        const int nw = half ? nwall[kNeg + k] : nwall[k];
        nv[k] = ((const float4*)(W_ctx + (size_t)nw * kE))[l32];
    }

    float pos = dot4(c, x);
    float negp[kNeg];
    #pragma unroll
    for (int k = 0; k < kNeg; ++k)
        negp[k] = dot4(c, nv[k]);

    // 5-step butterfly within each 32-lane half (xor masks < 32 stay in-half).
    #pragma unroll
    for (int off = 16; off > 0; off >>= 1) {
        pos += __shfl_xor(pos, off);
        #pragma unroll
        for (int k = 0; k < kNeg; ++k)
            negp[k] += __shfl_xor(negp[k], off);
    }
    // Every lane now holds all 11 full dot products for its example.

    // Distribute the 11 log_sigmoid evaluations across lanes 0..10 of the half.
    float v = pos;                          // lane 0: positive score
    #pragma unroll
    for (int k = 0; k < kNeg; ++k)
        v = (l32 == k + 1) ? -negp[k] : v;  // lanes 1..10: negated neg scores
    float s = (l32 < 1 + kNeg) ? log_sigmoid(v) : 0.0f;

    // Sum the 11 terms within the half (5 steps), then across halves (1 step).
    #pragma unroll
    for (int off = 16; off > 0; off >>= 1)
        s += __shfl_xor(s, off);
    s += __shfl_xor(s, 32);

    __shared__ float smem[kWavesPerBlock];
    if (lane == 0) smem[wave] = s;
    __syncthreads();
    if (threadIdx.x == 0)
        partials[blockIdx.x] = smem[0] + smem[1] + smem[2] + smem[3];
}

__global__ __launch_bounds__(256) void w2v_reduce_kernel(
    const float* __restrict__ partials,
    float*       __restrict__ out)
{
    float acc = 0.0f;
    for (int i = threadIdx.x; i < kBlocks; i += 256)
        acc += partials[i];

    #pragma unroll
    for (int off = 32; off > 0; off >>= 1)
        acc += __shfl_xor(acc, off);

    __shared__ float smem[4];
    const int lane = threadIdx.x & 63;
    const int wave = threadIdx.x >> 6;
    if (lane == 0) smem[wave] = acc;
    __syncthreads();
    if (threadIdx.x == 0) {
        const float total = smem[0] + smem[1] + smem[2] + smem[3];
        out[0] = -total / (float)kB;
    }
}

extern "C" void kernel_launch(void* const* d_in, const int* in_sizes, int n_in,
                              void* d_out, int out_size, void* d_ws, size_t ws_size,
                              hipStream_t stream) {
    const int*   input_word   = (const int*)d_in[0];
    const int*   context_word = (const int*)d_in[1];
    const int*   noise_words  = (const int*)d_in[2];
    const float* W_in         = (const float*)d_in[3];
    const float* W_ctx        = (const float*)d_in[4];
    float*       out          = (float*)d_out;
    float*       partials     = (float*)d_ws;   // kBlocks floats (8 KiB)

    w2v_loss_kernel<<<kBlocks, 256, 0, stream>>>(
        input_word, context_word, noise_words, W_in, W_ctx, partials);
    w2v_reduce_kernel<<<1, 256, 0, stream>>>(partials, out);
}